// Round 1
// baseline (3093.427 us; speedup 1.0000x reference)
//
#include <hip/hip_runtime.h>
#include <float.h>
#include <math.h>

// Shapes are fixed by setup_inputs(): B=8, T=4096, C=1024, requested_r=2048.
constexpr int B_ = 8;
constexpr int T_ = 4096;
constexpr int C_ = 1024;
constexpr int K_ = 2048;   // T - requested_r

// ---------------- kernel 1: per-token squared norm (fp64) + 1/(norm+1e-12) (fp32) --
__global__ __launch_bounds__(256) void score_kernel(
    const float* __restrict__ x, double* __restrict__ sd, float* __restrict__ rnorm)
{
  int wid = threadIdx.x >> 6, lane = threadIdx.x & 63;
  int token = blockIdx.x * 4 + wid;               // one wave per token
  const float* row = x + (size_t)token * C_;
  double s = 0.0;
  #pragma unroll
  for (int i = 0; i < 4; i++) {
    float4 v = *reinterpret_cast<const float4*>(&row[lane * 4 + i * 256]);
    s += (double)v.x * v.x + (double)v.y * v.y + (double)v.z * v.z + (double)v.w * v.w;
  }
  #pragma unroll
  for (int off = 32; off > 0; off >>= 1) s += __shfl_down(s, off);
  if (lane == 0) {
    sd[token] = s;
    rnorm[token] = (float)(1.0 / (sqrt(s) + 1e-12));
  }
}

// ---------------- kernel 2a: rank-count top-K flags (fp64 keys, exact total order) --
__global__ __launch_bounds__(256) void rank_kernel(
    const double* __restrict__ sd, int* __restrict__ flag)
{
  int b = blockIdx.y;
  int t = blockIdx.x * 256 + threadIdx.x;
  __shared__ double sh[T_];                       // 32 KiB
  for (int i = threadIdx.x; i < T_; i += 256)
    sh[i] = (i == 0) ? DBL_MAX : sd[b * T_ + i];  // CLS protection
  __syncthreads();
  double key = sh[t];
  int cnt = 0;
  #pragma unroll 4
  for (int j = 0; j < T_; j++) {
    double sj = sh[j];
    cnt += (sj > key) || (sj == key && j < t);    // (score desc, idx asc) total order
  }
  flag[b * T_ + t] = (cnt < K_) ? 1 : 0;
}

// ---------------- kernel 2b: per-batch prefix over flags -> keep_idx (sorted), kpos --
__global__ __launch_bounds__(256) void select_kernel(
    const int* __restrict__ flag, int* __restrict__ kpos, int* __restrict__ keep_idx)
{
  int b = blockIdx.x, tid = threadIdx.x;
  __shared__ int sums[256];
  int f[16], s = 0;
  int base = b * T_ + tid * 16;
  #pragma unroll
  for (int i = 0; i < 16; i++) { f[i] = flag[base + i]; s += f[i]; }
  sums[tid] = s;
  __syncthreads();
  for (int off = 1; off < 256; off <<= 1) {
    int v = 0;
    if (tid >= off) v = sums[tid - off];
    __syncthreads();
    if (tid >= off) sums[tid] += v;
    __syncthreads();
  }
  int run = (tid == 0) ? 0 : sums[tid - 1];
  #pragma unroll
  for (int i = 0; i < 16; i++) {
    int t = tid * 16 + i;
    if (f[i]) { keep_idx[b * K_ + run] = t; kpos[b * T_ + t] = run; run++; }
    else kpos[b * T_ + t] = -1;
  }
}

// ---------------- zero scratch (cnt + refine queue counter) ----------------
__global__ void zero_kernel(int* __restrict__ cnt, int* __restrict__ nref)
{
  int i = blockIdx.x * 256 + threadIdx.x;
  if (i < B_ * K_) cnt[i] = 0;
  if (i == 0) *nref = 0;
}

// ---------------- kernel 3: similarity argmax (fp32 tiled GEMM + top-2 epilogue) ----
// sim(t,k) = x_t . (x_{keep_k} * rnorm_k)   (A-side normalization dropped: argmax-invariant)
constexpr int TT = 64, KT = 64, CCH = 16;
constexpr float REFINE_DELTA = 5e-5f;  // ~25x fp32 dot-product noise at C=1024

__global__ __launch_bounds__(256) void argmax_kernel(
    const float* __restrict__ x, const float* __restrict__ rnorm,
    const int* __restrict__ keep_idx, const int* __restrict__ kpos,
    int* __restrict__ assign, int* __restrict__ rlist, int* __restrict__ nref)
{
  int b = blockIdx.y;
  int t0 = blockIdx.x * TT;
  const float* xb = x + (size_t)b * T_ * C_;
  __shared__ __align__(16) float As[CCH][TT];   // [c][t]
  __shared__ __align__(16) float Bs[CCH][KT];   // [c][k]
  __shared__ float redv[TT][17];
  __shared__ float reds[TT][17];
  __shared__ int   redk[TT][17];
  int tid = threadIdx.x;
  int tx = tid & 15, ty = tid >> 4;
  int lrow = tid >> 2;              // 0..63 staging row
  int lc4  = (tid & 3) << 2;        // 0,4,8,12 staging col

  const float* arow = xb + (size_t)(t0 + lrow) * C_;

  float best[4], second[4];
  int bestk[4];
  #pragma unroll
  for (int i = 0; i < 4; i++) { best[i] = -FLT_MAX; second[i] = -FLT_MAX; bestk[i] = 0; }

  for (int k0 = 0; k0 < K_; k0 += KT) {
    int ktok = keep_idx[b * K_ + k0 + lrow];
    float scale = rnorm[b * T_ + ktok];
    const float* brow = xb + (size_t)ktok * C_;

    float4 av = *reinterpret_cast<const float4*>(&arow[lc4]);
    float4 bv = *reinterpret_cast<const float4*>(&brow[lc4]);

    float acc[4][4];
    #pragma unroll
    for (int i = 0; i < 4; i++)
      #pragma unroll
      for (int j = 0; j < 4; j++) acc[i][j] = 0.f;

    for (int c0 = 0; c0 < C_; c0 += CCH) {
      __syncthreads();
      As[lc4+0][lrow] = av.x; As[lc4+1][lrow] = av.y;
      As[lc4+2][lrow] = av.z; As[lc4+3][lrow] = av.w;
      Bs[lc4+0][lrow] = bv.x * scale; Bs[lc4+1][lrow] = bv.y * scale;
      Bs[lc4+2][lrow] = bv.z * scale; Bs[lc4+3][lrow] = bv.w * scale;
      __syncthreads();
      if (c0 + CCH < C_) {  // prefetch next chunk: latency hides under compute
        av = *reinterpret_cast<const float4*>(&arow[c0 + CCH + lc4]);
        bv = *reinterpret_cast<const float4*>(&brow[c0 + CCH + lc4]);
      }
      #pragma unroll
      for (int cc = 0; cc < CCH; cc++) {
        float4 a  = *reinterpret_cast<const float4*>(&As[cc][ty << 2]);
        float4 bb = *reinterpret_cast<const float4*>(&Bs[cc][tx << 2]);
        acc[0][0] += a.x*bb.x; acc[0][1] += a.x*bb.y; acc[0][2] += a.x*bb.z; acc[0][3] += a.x*bb.w;
        acc[1][0] += a.y*bb.x; acc[1][1] += a.y*bb.y; acc[1][2] += a.y*bb.z; acc[1][3] += a.y*bb.w;
        acc[2][0] += a.z*bb.x; acc[2][1] += a.z*bb.y; acc[2][2] += a.z*bb.z; acc[2][3] += a.z*bb.w;
        acc[3][0] += a.w*bb.x; acc[3][1] += a.w*bb.y; acc[3][2] += a.w*bb.z; acc[3][3] += a.w*bb.w;
      }
    }
    // k ascending (tiles ascend, j ascends) + strict '>' == first-max semantics
    #pragma unroll
    for (int i = 0; i < 4; i++) {
      #pragma unroll
      for (int j = 0; j < 4; j++) {
        float v = acc[i][j];
        int kg = k0 + (tx << 2) + j;
        if (v > best[i]) { second[i] = best[i]; best[i] = v; bestk[i] = kg; }
        else if (v > second[i]) second[i] = v;
      }
    }
  }

  __syncthreads();
  #pragma unroll
  for (int i = 0; i < 4; i++) {
    int tl = (ty << 2) + i;
    redv[tl][tx] = best[i];
    reds[tl][tx] = second[i];
    redk[tl][tx] = bestk[i];
  }
  __syncthreads();

  if (tid < TT) {
    float bv2 = redv[tid][0]; int bk = redk[tid][0]; int win = 0;
    for (int j = 1; j < 16; j++) {
      float v = redv[tid][j]; int k2 = redk[tid][j];
      if (v > bv2 || (v == bv2 && k2 < bk)) { bv2 = v; bk = k2; win = j; }
    }
    float sec = reds[tid][win];
    for (int j = 0; j < 16; j++)
      if (j != win) sec = fmaxf(sec, redv[tid][j]);

    int t = t0 + tid;
    int kp = kpos[b * T_ + t];
    if (kp >= 0) {
      assign[b * T_ + t] = kp;      // kept centers self-assign (reference override)
    } else {
      assign[b * T_ + t] = bk;
      if ((bv2 - sec) * rnorm[b * T_ + t] < REFINE_DELTA) {
        int qi = atomicAdd(nref, 1);
        rlist[qi] = b * T_ + t;
      }
    }
  }
}

// ---------------- kernel 3b: fp64 re-score of near-tie tokens ----------------
__global__ __launch_bounds__(256) void refine_kernel(
    const float* __restrict__ x, const double* __restrict__ sd,
    const int* __restrict__ keep_idx, const int* __restrict__ nref,
    const int* __restrict__ rlist, int* __restrict__ assign)
{
  __shared__ __align__(16) float xs[C_];
  __shared__ double rv[256];
  __shared__ int rk[256];
  int n = *nref;
  for (int qi = blockIdx.x; qi < n; qi += gridDim.x) {
    int bt = rlist[qi];
    int b = bt >> 12;
    const float* xb = x + (size_t)b * T_ * C_;
    const float* xt = xb + (size_t)(bt & (T_ - 1)) * C_;
    __syncthreads();
    for (int i = threadIdx.x; i < C_; i += 256) xs[i] = xt[i];
    __syncthreads();
    double bv = -DBL_MAX; int bk = 0x7fffffff;
    for (int k = threadIdx.x; k < K_; k += 256) {
      int kt = keep_idx[b * K_ + k];
      const float* xr = xb + (size_t)kt * C_;
      double s = 0.0;
      for (int c = 0; c < C_; c += 4) {
        float4 v = *reinterpret_cast<const float4*>(&xr[c]);
        s += (double)xs[c] * v.x + (double)xs[c+1] * v.y
           + (double)xs[c+2] * v.z + (double)xs[c+3] * v.w;
      }
      s /= sqrt(sd[b * T_ + kt]);
      if (s > bv || (s == bv && k < bk)) { bv = s; bk = k; }
    }
    rv[threadIdx.x] = bv; rk[threadIdx.x] = bk;
    __syncthreads();
    for (int off = 128; off > 0; off >>= 1) {
      if (threadIdx.x < off) {
        double v2 = rv[threadIdx.x + off]; int k2 = rk[threadIdx.x + off];
        if (v2 > rv[threadIdx.x] || (v2 == rv[threadIdx.x] && k2 < rk[threadIdx.x])) {
          rv[threadIdx.x] = v2; rk[threadIdx.x] = k2;
        }
      }
      __syncthreads();
    }
    if (threadIdx.x == 0) assign[bt] = rk[0];
    __syncthreads();
  }
}

// ---------------- kernels 4: counting-sort cluster lists ----------------
__global__ void count_kernel(const int* __restrict__ assign, int* __restrict__ cnt)
{
  int i = blockIdx.x * 256 + threadIdx.x;
  int b = i >> 12;
  atomicAdd(&cnt[b * K_ + assign[i]], 1);
}

__global__ __launch_bounds__(256) void scan_kernel(
    const int* __restrict__ cnt, int* __restrict__ offs, int* __restrict__ cursor)
{
  int b = blockIdx.x, tid = threadIdx.x;
  __shared__ int sums[256];
  int v[8], s = 0;
  int base = b * K_ + tid * 8;
  #pragma unroll
  for (int i = 0; i < 8; i++) { v[i] = cnt[base + i]; s += v[i]; }
  sums[tid] = s;
  __syncthreads();
  for (int off = 1; off < 256; off <<= 1) {
    int t2 = 0;
    if (tid >= off) t2 = sums[tid - off];
    __syncthreads();
    if (tid >= off) sums[tid] += t2;
    __syncthreads();
  }
  int run = (tid == 0) ? 0 : sums[tid - 1];
  #pragma unroll
  for (int i = 0; i < 8; i++) { offs[base + i] = run; cursor[base + i] = run; run += v[i]; }
}

__global__ void scatter_kernel(const int* __restrict__ assign,
                               int* __restrict__ cursor, int* __restrict__ lists)
{
  int i = blockIdx.x * 256 + threadIdx.x;
  int b = i >> 12, t = i & (T_ - 1);
  int p = atomicAdd(&cursor[b * K_ + assign[i]], 1);
  lists[b * T_ + p] = t;
}

// ---------------- kernel 5: segment mean + alpha blend ----------------
__global__ __launch_bounds__(256) void merge_kernel(
    const float* __restrict__ x, const int* __restrict__ keep_idx,
    const int* __restrict__ cnt, const int* __restrict__ offs,
    const int* __restrict__ lists, float* __restrict__ out)
{
  int b = blockIdx.y, k = blockIdx.x;
  int m = cnt[b * K_ + k], off = offs[b * K_ + k];
  const float* xb = x + (size_t)b * T_ * C_;
  int c4 = threadIdx.x * 4;
  float sx = 0.f, sy = 0.f, sz = 0.f, sw = 0.f;
  for (int i = 0; i < m; i++) {
    int tok = lists[b * T_ + off + i];
    float4 v = *reinterpret_cast<const float4*>(&xb[(size_t)tok * C_ + c4]);
    sx += v.x; sy += v.y; sz += v.z; sw += v.w;
  }
  int kt = keep_idx[b * K_ + k];
  float4 xk = *reinterpret_cast<const float4*>(&xb[(size_t)kt * C_ + c4]);
  float fm = (float)m;
  float4 o;
  o.x = 0.85f * xk.x + 0.15f * (sx / fm);
  o.y = 0.85f * xk.y + 0.15f * (sy / fm);
  o.z = 0.85f * xk.z + 0.15f * (sz / fm);
  o.w = 0.85f * xk.w + 0.15f * (sw / fm);
  *reinterpret_cast<float4*>(&out[((size_t)b * K_ + k) * C_ + c4]) = o;
}

// ---------------- launch ----------------
extern "C" void kernel_launch(void* const* d_in, const int* in_sizes, int n_in,
                              void* d_out, int out_size, void* d_ws, size_t ws_size,
                              hipStream_t stream)
{
  const float* x = (const float*)d_in[0];
  float* out = (float*)d_out;

  char* w = (char*)d_ws;
  double* sd    = (double*)w;  w += sizeof(double) * B_ * T_;
  float* rnorm  = (float*)w;   w += sizeof(float) * B_ * T_;
  int* flag     = (int*)w;     w += sizeof(int) * B_ * T_;
  int* kpos     = (int*)w;     w += sizeof(int) * B_ * T_;
  int* keep_idx = (int*)w;     w += sizeof(int) * B_ * K_;
  int* assign   = (int*)w;     w += sizeof(int) * B_ * T_;
  int* cnt      = (int*)w;     w += sizeof(int) * B_ * K_;
  int* offs     = (int*)w;     w += sizeof(int) * B_ * K_;
  int* cursor   = (int*)w;     w += sizeof(int) * B_ * K_;
  int* lists    = (int*)w;     w += sizeof(int) * B_ * T_;
  int* rlist    = (int*)w;     w += sizeof(int) * B_ * T_;
  int* nref     = (int*)w;     w += 256;

  score_kernel<<<B_ * T_ / 4, 256, 0, stream>>>(x, sd, rnorm);
  rank_kernel<<<dim3(T_ / 256, B_), 256, 0, stream>>>(sd, flag);
  select_kernel<<<B_, 256, 0, stream>>>(flag, kpos, keep_idx);
  zero_kernel<<<(B_ * K_ + 255) / 256, 256, 0, stream>>>(cnt, nref);
  argmax_kernel<<<dim3(T_ / TT, B_), 256, 0, stream>>>(x, rnorm, keep_idx, kpos,
                                                       assign, rlist, nref);
  refine_kernel<<<256, 256, 0, stream>>>(x, sd, keep_idx, nref, rlist, assign);
  count_kernel<<<B_ * T_ / 256, 256, 0, stream>>>(assign, cnt);
  scan_kernel<<<B_, 256, 0, stream>>>(cnt, offs, cursor);
  scatter_kernel<<<B_ * T_ / 256, 256, 0, stream>>>(assign, cursor, lists);
  merge_kernel<<<dim3(K_, B_), 256, 0, stream>>>(x, keep_idx, cnt, offs, lists, out);
}

// Round 2
// 1308.479 us; speedup vs baseline: 2.3641x; 2.3641x over previous
//
#include <hip/hip_runtime.h>
#include <hip/hip_bf16.h>
#include <float.h>
#include <math.h>

// Shapes fixed by setup_inputs(): B=8, T=4096, C=1024, requested_r=2048.
constexpr int B_ = 8;
constexpr int T_ = 4096;
constexpr int C_ = 1024;
constexpr int K_ = 2048;

constexpr int BM = 128, BN = 128, BK = 32;
constexpr int NB = K_ / BN;            // 16 n-blocks
constexpr float REFINE_DELTA = 2e-5f;  // cosine-gap flag threshold (~50 sigma of split-bf16 err)

typedef short bf16x8 __attribute__((ext_vector_type(8)));
typedef float f32x4  __attribute__((ext_vector_type(4)));

__device__ __forceinline__ void gload16(const ushort* g, ushort* l) {
  __builtin_amdgcn_global_load_lds(
      (const __attribute__((address_space(1))) unsigned int*)g,
      (__attribute__((address_space(3))) unsigned int*)l, 16, 0, 0);
}

// ---------------- kernel 0: split x into bf16 hi + bf16 lo ----------------
__global__ __launch_bounds__(256) void split_kernel(
    const float* __restrict__ x, ushort* __restrict__ xh, ushort* __restrict__ xl)
{
  size_t i = ((size_t)blockIdx.x * 256 + threadIdx.x) * 4;
  float4 v = *reinterpret_cast<const float4*>(&x[i]);
  ushort4 h, l;
  {
    __hip_bfloat16 hb;
    hb = __float2bfloat16(v.x); h.x = *(ushort*)&hb;
    { __hip_bfloat16 lb = __float2bfloat16(v.x - __bfloat162float(hb)); l.x = *(ushort*)&lb; }
    hb = __float2bfloat16(v.y); h.y = *(ushort*)&hb;
    { __hip_bfloat16 lb = __float2bfloat16(v.y - __bfloat162float(hb)); l.y = *(ushort*)&lb; }
    hb = __float2bfloat16(v.z); h.z = *(ushort*)&hb;
    { __hip_bfloat16 lb = __float2bfloat16(v.z - __bfloat162float(hb)); l.z = *(ushort*)&lb; }
    hb = __float2bfloat16(v.w); h.w = *(ushort*)&hb;
    { __hip_bfloat16 lb = __float2bfloat16(v.w - __bfloat162float(hb)); l.w = *(ushort*)&lb; }
  }
  *reinterpret_cast<ushort4*>(&xh[i]) = h;
  *reinterpret_cast<ushort4*>(&xl[i]) = l;
}

// ---------------- kernel 1: per-token squared norm (fp64) + 1/norm (fp32) --
__global__ __launch_bounds__(256) void score_kernel(
    const float* __restrict__ x, double* __restrict__ sd, float* __restrict__ rnorm)
{
  int wid = threadIdx.x >> 6, lane = threadIdx.x & 63;
  int token = blockIdx.x * 4 + wid;
  const float* row = x + (size_t)token * C_;
  double s = 0.0;
  #pragma unroll
  for (int i = 0; i < 4; i++) {
    float4 v = *reinterpret_cast<const float4*>(&row[lane * 4 + i * 256]);
    s += (double)v.x * v.x + (double)v.y * v.y + (double)v.z * v.z + (double)v.w * v.w;
  }
  #pragma unroll
  for (int off = 32; off > 0; off >>= 1) s += __shfl_down(s, off);
  if (lane == 0) {
    sd[token] = s;
    rnorm[token] = (float)(1.0 / (sqrt(s) + 1e-12));
  }
}

// ---------------- kernel 2a: rank-count top-K flags (fp64 keys) ----------------
__global__ __launch_bounds__(256) void rank_kernel(
    const double* __restrict__ sd, int* __restrict__ flag)
{
  int b = blockIdx.y;
  int t = blockIdx.x * 256 + threadIdx.x;
  __shared__ double sh[T_];
  for (int i = threadIdx.x; i < T_; i += 256)
    sh[i] = (i == 0) ? DBL_MAX : sd[b * T_ + i];
  __syncthreads();
  double key = sh[t];
  int cnt = 0;
  #pragma unroll 4
  for (int j = 0; j < T_; j++) {
    double sj = sh[j];
    cnt += (sj > key) || (sj == key && j < t);
  }
  flag[b * T_ + t] = (cnt < K_) ? 1 : 0;
}

// ---------------- kernel 2b: prefix over flags -> keep_idx, kpos ----------------
__global__ __launch_bounds__(256) void select_kernel(
    const int* __restrict__ flag, int* __restrict__ kpos, int* __restrict__ keep_idx)
{
  int b = blockIdx.x, tid = threadIdx.x;
  __shared__ int sums[256];
  int f[16], s = 0;
  int base = b * T_ + tid * 16;
  #pragma unroll
  for (int i = 0; i < 16; i++) { f[i] = flag[base + i]; s += f[i]; }
  sums[tid] = s;
  __syncthreads();
  for (int off = 1; off < 256; off <<= 1) {
    int v = 0;
    if (tid >= off) v = sums[tid - off];
    __syncthreads();
    if (tid >= off) sums[tid] += v;
    __syncthreads();
  }
  int run = (tid == 0) ? 0 : sums[tid - 1];
  #pragma unroll
  for (int i = 0; i < 16; i++) {
    int t = tid * 16 + i;
    if (f[i]) { keep_idx[b * K_ + run] = t; kpos[b * T_ + t] = run; run++; }
    else kpos[b * T_ + t] = -1;
  }
}

// ---------------- zero scratch ----------------
__global__ void zero_kernel(int* __restrict__ cnt, int* __restrict__ nref)
{
  int i = blockIdx.x * 256 + threadIdx.x;
  if (i < B_ * K_) cnt[i] = 0;
  if (i == 0) *nref = 0;
}

// ---------------- kernel 3: split-bf16 MFMA similarity + per-tile top-2 ----------
// dot(t,k) ~= hh + hl + lh accumulated in one fp32 MFMA accumulator.
// Grid (NB, T_/BM, B_), 256 threads (4 waves, each 64x64 sub-tile).
__global__ __launch_bounds__(256) void mfma_argmax_kernel(
    const ushort* __restrict__ xh, const ushort* __restrict__ xl,
    const float* __restrict__ rnorm, const int* __restrict__ keep_idx,
    float* __restrict__ pb, float* __restrict__ ps, int* __restrict__ pk)
{
  // LDS: [tile: Ah,Al,Bh,Bl][c-chunk 0..3][row 0..127][8 bf16] = 32 KiB
  __shared__ __align__(16) ushort lds[4][4][128][8];
  __shared__ float redb[2][128];
  __shared__ float redsec[2][128];
  __shared__ int   redk[2][128];

  int b  = blockIdx.z;
  int m0 = blockIdx.y * BM;
  int n0 = blockIdx.x * BN;
  int tid = threadIdx.x;
  int lane = tid & 63, wave = tid >> 6;
  int quad = lane >> 4, col = lane & 15;
  int wm = wave >> 1, wn = wave & 1;

  // staging: thread -> row (tid&127), c-chunk pair (tid>>7, 2+(tid>>7))
  int srow = tid & 127;
  int sc8  = (tid >> 7) * 8;   // element offset of first chunk

  const ushort* ga_h = xh + (size_t)(b * T_ + m0 + srow) * C_;
  const ushort* ga_l = xl + (size_t)(b * T_ + m0 + srow) * C_;
  int ktok_s = keep_idx[b * K_ + n0 + srow];
  const ushort* gb_h = xh + (size_t)(b * T_ + ktok_s) * C_;
  const ushort* gb_l = xl + (size_t)(b * T_ + ktok_s) * C_;

  ushort* lA_h = &lds[0][0][0][0];
  ushort* lA_l = &lds[1][0][0][0];
  ushort* lB_h = &lds[2][0][0][0];
  ushort* lB_l = &lds[3][0][0][0];
  int ldst = tid * 8;          // ushort offset of this thread's 16B slot

  // epilogue scales / candidate ids (stable across K-loop)
  float scale[4]; int ncand[4];
  #pragma unroll
  for (int j = 0; j < 4; j++) {
    int nn = n0 + wn * 64 + j * 16 + col;
    ncand[j] = nn;
    scale[j] = rnorm[b * T_ + keep_idx[b * K_ + nn]];
  }

  f32x4 acc[4][4];
  #pragma unroll
  for (int i = 0; i < 4; i++)
    #pragma unroll
    for (int j = 0; j < 4; j++) acc[i][j] = (f32x4)0.f;

  for (int ks = 0; ks < C_ / BK; ks++) {
    int k0 = ks * BK;
    __syncthreads();   // previous iteration's reads complete
    gload16(ga_h + k0 + sc8,      lA_h + ldst);
    gload16(ga_h + k0 + 16 + sc8, lA_h + ldst + 2048);
    gload16(ga_l + k0 + sc8,      lA_l + ldst);
    gload16(ga_l + k0 + 16 + sc8, lA_l + ldst + 2048);
    gload16(gb_h + k0 + sc8,      lB_h + ldst);
    gload16(gb_h + k0 + 16 + sc8, lB_h + ldst + 2048);
    gload16(gb_l + k0 + sc8,      lB_l + ldst);
    gload16(gb_l + k0 + 16 + sc8, lB_l + ldst + 2048);
    __syncthreads();   // staging drained (compiler emits vmcnt(0) before barrier)

    bf16x8 fa_h[4], fa_l[4], fb_h[4], fb_l[4];
    #pragma unroll
    for (int i = 0; i < 4; i++) {
      int row = wm * 64 + i * 16 + col;
      fa_h[i] = *reinterpret_cast<const bf16x8*>(&lds[0][quad][row][0]);
      fa_l[i] = *reinterpret_cast<const bf16x8*>(&lds[1][quad][row][0]);
    }
    #pragma unroll
    for (int j = 0; j < 4; j++) {
      int row = wn * 64 + j * 16 + col;
      fb_h[j] = *reinterpret_cast<const bf16x8*>(&lds[2][quad][row][0]);
      fb_l[j] = *reinterpret_cast<const bf16x8*>(&lds[3][quad][row][0]);
    }
    #pragma unroll
    for (int i = 0; i < 4; i++)
      #pragma unroll
      for (int j = 0; j < 4; j++) {
        acc[i][j] = __builtin_amdgcn_mfma_f32_16x16x32_bf16(fa_h[i], fb_h[j], acc[i][j], 0, 0, 0);
        acc[i][j] = __builtin_amdgcn_mfma_f32_16x16x32_bf16(fa_h[i], fb_l[j], acc[i][j], 0, 0, 0);
        acc[i][j] = __builtin_amdgcn_mfma_f32_16x16x32_bf16(fa_l[i], fb_h[j], acc[i][j], 0, 0, 0);
      }
  }

  // ---- epilogue: top-2 per token row over this block's 128 centers ----
  // C/D layout: col=lane&15 (n), row=quad*4+reg (m)
  #pragma unroll
  for (int i = 0; i < 4; i++) {
    #pragma unroll
    for (int r = 0; r < 4; r++) {
      float b1 = -FLT_MAX, b2 = -FLT_MAX; int k1 = 0;
      #pragma unroll
      for (int j = 0; j < 4; j++) {
        float v = acc[i][j][r] * scale[j];
        if (v > b1) { b2 = b1; b1 = v; k1 = ncand[j]; }
        else if (v > b2) b2 = v;
      }
      #pragma unroll
      for (int off = 1; off < 16; off <<= 1) {
        float ob1 = __shfl_xor(b1, off);
        float ob2 = __shfl_xor(b2, off);
        int   ok1 = __shfl_xor(k1, off);
        if (ob1 > b1 || (ob1 == b1 && ok1 < k1)) { b2 = fmaxf(b1, ob2); b1 = ob1; k1 = ok1; }
        else b2 = fmaxf(b2, ob1);
      }
      if (col == 0) {
        int tl = wm * 64 + i * 16 + quad * 4 + r;
        redb[wn][tl] = b1; redsec[wn][tl] = b2; redk[wn][tl] = k1;
      }
    }
  }
  __syncthreads();
  if (tid < 128) {
    float b1 = redb[0][tid], b2 = redsec[0][tid]; int k1 = redk[0][tid];
    float o1 = redb[1][tid], o2 = redsec[1][tid]; int ok = redk[1][tid];
    if (o1 > b1) { b2 = fmaxf(b1, o2); b1 = o1; k1 = ok; }  // wn=1 n-range higher: ties keep wn=0
    else b2 = fmaxf(b2, o1);
    size_t p = ((size_t)(b * NB + blockIdx.x)) * T_ + m0 + tid;
    pb[p] = b1; ps[p] = b2; pk[p] = k1;
  }
}

// ---------------- kernel 3b: merge partials -> assign + refine queue ----------------
__global__ __launch_bounds__(256) void reduce2_kernel(
    const float* __restrict__ pb, const float* __restrict__ ps, const int* __restrict__ pk,
    const float* __restrict__ rnorm, const int* __restrict__ kpos,
    int* __restrict__ assign, int* __restrict__ rlist, int* __restrict__ nref)
{
  int idx = blockIdx.x * 256 + threadIdx.x;   // b*T + t
  int b = idx >> 12, t = idx & (T_ - 1);
  float b1 = -FLT_MAX, b2 = -FLT_MAX; int k1 = 0;
  for (int nb = 0; nb < NB; nb++) {           // nb ascending => n ascending, '>' keeps first
    size_t p = ((size_t)(b * NB + nb)) * T_ + t;
    float v = pb[p], s = ps[p]; int k = pk[p];
    if (v > b1) { b2 = fmaxf(b1, s); b1 = v; k1 = k; }
    else b2 = fmaxf(b2, v);
  }
  int kp = kpos[idx];
  if (kp >= 0) assign[idx] = kp;
  else {
    assign[idx] = k1;
    if ((b1 - b2) * rnorm[idx] < REFINE_DELTA) {
      int qi = atomicAdd(nref, 1);
      rlist[qi] = idx;
    }
  }
}

// ---------------- kernel 3c: fp64 re-score of near-tie tokens ----------------
__global__ __launch_bounds__(256) void refine_kernel(
    const float* __restrict__ x, const double* __restrict__ sd,
    const int* __restrict__ keep_idx, const int* __restrict__ nref,
    const int* __restrict__ rlist, int* __restrict__ assign)
{
  __shared__ __align__(16) float xs[C_];
  __shared__ double rv[256];
  __shared__ int rk[256];
  int n = *nref;
  for (int qi = blockIdx.x; qi < n; qi += gridDim.x) {
    int bt = rlist[qi];
    int b = bt >> 12;
    const float* xb = x + (size_t)b * T_ * C_;
    const float* xt = xb + (size_t)(bt & (T_ - 1)) * C_;
    __syncthreads();
    for (int i = threadIdx.x; i < C_; i += 256) xs[i] = xt[i];
    __syncthreads();
    double bv = -DBL_MAX; int bk = 0x7fffffff;
    for (int k = threadIdx.x; k < K_; k += 256) {
      int kt = keep_idx[b * K_ + k];
      const float* xr = xb + (size_t)kt * C_;
      double s = 0.0;
      for (int c = 0; c < C_; c += 4) {
        float4 v = *reinterpret_cast<const float4*>(&xr[c]);
        s += (double)xs[c] * v.x + (double)xs[c+1] * v.y
           + (double)xs[c+2] * v.z + (double)xs[c+3] * v.w;
      }
      s /= sqrt(sd[b * T_ + kt]);
      if (s > bv || (s == bv && k < bk)) { bv = s; bk = k; }
    }
    rv[threadIdx.x] = bv; rk[threadIdx.x] = bk;
    __syncthreads();
    for (int off = 128; off > 0; off >>= 1) {
      if (threadIdx.x < off) {
        double v2 = rv[threadIdx.x + off]; int k2 = rk[threadIdx.x + off];
        if (v2 > rv[threadIdx.x] || (v2 == rv[threadIdx.x] && k2 < rk[threadIdx.x])) {
          rv[threadIdx.x] = v2; rk[threadIdx.x] = k2;
        }
      }
      __syncthreads();
    }
    if (threadIdx.x == 0) assign[bt] = rk[0];
    __syncthreads();
  }
}

// ---------------- kernels 4: counting-sort cluster lists ----------------
__global__ void count_kernel(const int* __restrict__ assign, int* __restrict__ cnt)
{
  int i = blockIdx.x * 256 + threadIdx.x;
  int b = i >> 12;
  atomicAdd(&cnt[b * K_ + assign[i]], 1);
}

__global__ __launch_bounds__(256) void scan_kernel(
    const int* __restrict__ cnt, int* __restrict__ offs, int* __restrict__ cursor)
{
  int b = blockIdx.x, tid = threadIdx.x;
  __shared__ int sums[256];
  int v[8], s = 0;
  int base = b * K_ + tid * 8;
  #pragma unroll
  for (int i = 0; i < 8; i++) { v[i] = cnt[base + i]; s += v[i]; }
  sums[tid] = s;
  __syncthreads();
  for (int off = 1; off < 256; off <<= 1) {
    int t2 = 0;
    if (tid >= off) t2 = sums[tid - off];
    __syncthreads();
    if (tid >= off) sums[tid] += t2;
    __syncthreads();
  }
  int run = (tid == 0) ? 0 : sums[tid - 1];
  #pragma unroll
  for (int i = 0; i < 8; i++) { offs[base + i] = run; cursor[base + i] = run; run += v[i]; }
}

__global__ void scatter_kernel(const int* __restrict__ assign,
                               int* __restrict__ cursor, int* __restrict__ lists)
{
  int i = blockIdx.x * 256 + threadIdx.x;
  int b = i >> 12, t = i & (T_ - 1);
  int p = atomicAdd(&cursor[b * K_ + assign[i]], 1);
  lists[b * T_ + p] = t;
}

// ---------------- kernel 5: segment mean + alpha blend ----------------
__global__ __launch_bounds__(256) void merge_kernel(
    const float* __restrict__ x, const int* __restrict__ keep_idx,
    const int* __restrict__ cnt, const int* __restrict__ offs,
    const int* __restrict__ lists, float* __restrict__ out)
{
  int b = blockIdx.y, k = blockIdx.x;
  int m = cnt[b * K_ + k], off = offs[b * K_ + k];
  const float* xb = x + (size_t)b * T_ * C_;
  int c4 = threadIdx.x * 4;
  float sx = 0.f, sy = 0.f, sz = 0.f, sw = 0.f;
  for (int i = 0; i < m; i++) {
    int tok = lists[b * T_ + off + i];
    float4 v = *reinterpret_cast<const float4*>(&xb[(size_t)tok * C_ + c4]);
    sx += v.x; sy += v.y; sz += v.z; sw += v.w;
  }
  int kt = keep_idx[b * K_ + k];
  float4 xk = *reinterpret_cast<const float4*>(&xb[(size_t)kt * C_ + c4]);
  float fm = (float)m;
  float4 o;
  o.x = 0.85f * xk.x + 0.15f * (sx / fm);
  o.y = 0.85f * xk.y + 0.15f * (sy / fm);
  o.z = 0.85f * xk.z + 0.15f * (sz / fm);
  o.w = 0.85f * xk.w + 0.15f * (sw / fm);
  *reinterpret_cast<float4*>(&out[((size_t)b * K_ + k) * C_ + c4]) = o;
}

// ---------------- launch ----------------
extern "C" void kernel_launch(void* const* d_in, const int* in_sizes, int n_in,
                              void* d_out, int out_size, void* d_ws, size_t ws_size,
                              hipStream_t stream)
{
  const float* x = (const float*)d_in[0];
  float* out = (float*)d_out;

  char* w = (char*)d_ws;
  ushort* xh    = (ushort*)w;  w += sizeof(ushort) * (size_t)B_ * T_ * C_;  // 67 MB
  ushort* xl    = (ushort*)w;  w += sizeof(ushort) * (size_t)B_ * T_ * C_;  // 67 MB
  float* pb     = (float*)w;   w += sizeof(float) * (size_t)B_ * NB * T_;   // 2 MB
  float* ps     = (float*)w;   w += sizeof(float) * (size_t)B_ * NB * T_;
  int*   pk     = (int*)w;     w += sizeof(int) * (size_t)B_ * NB * T_;
  double* sd    = (double*)w;  w += sizeof(double) * B_ * T_;
  float* rnorm  = (float*)w;   w += sizeof(float) * B_ * T_;
  int* flag     = (int*)w;     w += sizeof(int) * B_ * T_;
  int* kpos     = (int*)w;     w += sizeof(int) * B_ * T_;
  int* keep_idx = (int*)w;     w += sizeof(int) * B_ * K_;
  int* assign   = (int*)w;     w += sizeof(int) * B_ * T_;
  int* cnt      = (int*)w;     w += sizeof(int) * B_ * K_;
  int* offs     = (int*)w;     w += sizeof(int) * B_ * K_;
  int* cursor   = (int*)w;     w += sizeof(int) * B_ * K_;
  int* lists    = (int*)w;     w += sizeof(int) * B_ * T_;
  int* rlist    = (int*)w;     w += sizeof(int) * B_ * T_;
  int* nref     = (int*)w;     w += 256;

  split_kernel<<<(size_t)B_ * T_ * C_ / 4 / 256, 256, 0, stream>>>(x, xh, xl);
  score_kernel<<<B_ * T_ / 4, 256, 0, stream>>>(x, sd, rnorm);
  rank_kernel<<<dim3(T_ / 256, B_), 256, 0, stream>>>(sd, flag);
  select_kernel<<<B_, 256, 0, stream>>>(flag, kpos, keep_idx);
  zero_kernel<<<(B_ * K_ + 255) / 256, 256, 0, stream>>>(cnt, nref);
  mfma_argmax_kernel<<<dim3(NB, T_ / BM, B_), 256, 0, stream>>>(
      xh, xl, rnorm, keep_idx, pb, ps, pk);
  reduce2_kernel<<<B_ * T_ / 256, 256, 0, stream>>>(
      pb, ps, pk, rnorm, kpos, assign, rlist, nref);
  refine_kernel<<<256, 256, 0, stream>>>(x, sd, keep_idx, nref, rlist, assign);
  count_kernel<<<B_ * T_ / 256, 256, 0, stream>>>(assign, cnt);
  scan_kernel<<<B_, 256, 0, stream>>>(cnt, offs, cursor);
  scatter_kernel<<<B_ * T_ / 256, 256, 0, stream>>>(assign, cursor, lists);
  merge_kernel<<<dim3(K_, B_), 256, 0, stream>>>(x, keep_idx, cnt, offs, lists, out);
}

// Round 3
// 1202.945 us; speedup vs baseline: 2.5715x; 1.0877x over previous
//
#include <hip/hip_runtime.h>
#include <hip/hip_bf16.h>
#include <float.h>
#include <math.h>

// Shapes fixed by setup_inputs(): B=8, T=4096, C=1024, requested_r=2048.
constexpr int B_ = 8;
constexpr int T_ = 4096;
constexpr int C_ = 1024;
constexpr int K_ = 2048;

constexpr int BM = 128, BN = 128, BK = 32;
constexpr int NB = K_ / BN;            // 16 n-blocks
constexpr float REFINE_DELTA = 1e-5f;  // ~55 sigma of split-bf16 cosine noise (sigma~1.8e-7)

typedef short bf16x8 __attribute__((ext_vector_type(8)));
typedef float f32x4  __attribute__((ext_vector_type(4)));

__device__ __forceinline__ void gload16(const ushort* g, ushort* l) {
  __builtin_amdgcn_global_load_lds(
      (const __attribute__((address_space(1))) unsigned int*)g,
      (__attribute__((address_space(3))) unsigned int*)l, 16, 0, 0);
}

// ---------------- kernel 0: fused split (bf16 hi/lo) + fp64 squared norm ----------
// One block per token row: reads x once, writes xh/xl, reduces |x|^2 in fp64.
__global__ __launch_bounds__(256) void split_score_kernel(
    const float* __restrict__ x, ushort* __restrict__ xh, ushort* __restrict__ xl,
    double* __restrict__ sd, float* __restrict__ rnorm)
{
  int row = blockIdx.x;                 // b*T + t
  size_t base = (size_t)row * C_;
  int i4 = threadIdx.x * 4;
  float4 v = *reinterpret_cast<const float4*>(&x[base + i4]);
  ushort4 h, l;
  {
    __hip_bfloat16 hb, lb;
    hb = __float2bfloat16(v.x); lb = __float2bfloat16(v.x - __bfloat162float(hb));
    h.x = *(ushort*)&hb; l.x = *(ushort*)&lb;
    hb = __float2bfloat16(v.y); lb = __float2bfloat16(v.y - __bfloat162float(hb));
    h.y = *(ushort*)&hb; l.y = *(ushort*)&lb;
    hb = __float2bfloat16(v.z); lb = __float2bfloat16(v.z - __bfloat162float(hb));
    h.z = *(ushort*)&hb; l.z = *(ushort*)&lb;
    hb = __float2bfloat16(v.w); lb = __float2bfloat16(v.w - __bfloat162float(hb));
    h.w = *(ushort*)&hb; l.w = *(ushort*)&lb;
  }
  *reinterpret_cast<ushort4*>(&xh[base + i4]) = h;
  *reinterpret_cast<ushort4*>(&xl[base + i4]) = l;
  double s = (double)v.x * v.x + (double)v.y * v.y
           + (double)v.z * v.z + (double)v.w * v.w;
  #pragma unroll
  for (int off = 32; off > 0; off >>= 1) s += __shfl_down(s, off);
  __shared__ double ws4[4];
  int lane = threadIdx.x & 63, wave = threadIdx.x >> 6;
  if (lane == 0) ws4[wave] = s;
  __syncthreads();
  if (threadIdx.x == 0) {
    double t = ws4[0] + ws4[1] + ws4[2] + ws4[3];
    sd[row] = t;
    rnorm[row] = (float)(1.0 / (sqrt(t) + 1e-12));
  }
}

// ---------------- kernel 2a: rank-count top-K flags (fp64 keys, exact total order) --
// 2 threads per token (half-scan each) -> 256 blocks for latency hiding.
__global__ __launch_bounds__(256) void rank_kernel(
    const double* __restrict__ sd, int* __restrict__ flag)
{
  int b = blockIdx.y;
  __shared__ double sh[T_];
  for (int i = threadIdx.x; i < T_; i += 256)
    sh[i] = (i == 0) ? DBL_MAX : sd[b * T_ + i];   // CLS protection
  __syncthreads();
  int t = blockIdx.x * 128 + (threadIdx.x >> 1);
  int half = threadIdx.x & 1;
  double key = sh[t];
  int cnt = 0;
  int j0 = half * 2048;
  #pragma unroll 4
  for (int jj = 0; jj < 2048; jj++) {
    int j = j0 + jj;
    double sj = sh[j];
    cnt += (sj > key) || (sj == key && j < t);     // (score desc, idx asc) total order
  }
  cnt += __shfl_xor(cnt, 1);
  if (half == 0) flag[b * T_ + t] = (cnt < K_) ? 1 : 0;
}

// ---------------- kernel 2b: prefix over flags -> keep_idx (sorted), kpos ----------
__global__ __launch_bounds__(256) void select_kernel(
    const int* __restrict__ flag, int* __restrict__ kpos, int* __restrict__ keep_idx)
{
  int b = blockIdx.x, tid = threadIdx.x;
  __shared__ int sums[256];
  int f[16], s = 0;
  int base = b * T_ + tid * 16;
  #pragma unroll
  for (int i = 0; i < 16; i++) { f[i] = flag[base + i]; s += f[i]; }
  sums[tid] = s;
  __syncthreads();
  for (int off = 1; off < 256; off <<= 1) {
    int v = 0;
    if (tid >= off) v = sums[tid - off];
    __syncthreads();
    if (tid >= off) sums[tid] += v;
    __syncthreads();
  }
  int run = (tid == 0) ? 0 : sums[tid - 1];
  #pragma unroll
  for (int i = 0; i < 16; i++) {
    int t = tid * 16 + i;
    if (f[i]) { keep_idx[b * K_ + run] = t; kpos[b * T_ + t] = run; run++; }
    else kpos[b * T_ + t] = -1;
  }
}

// ---------------- zero scratch ----------------
__global__ void zero_kernel(int* __restrict__ cnt, int* __restrict__ nref)
{
  int i = blockIdx.x * 256 + threadIdx.x;
  if (i < B_ * K_) cnt[i] = 0;
  if (i == 0) *nref = 0;
}

// ---------------- kernel 3: split-bf16 MFMA similarity, double-buffered staging ----
// dot(t,k) ~= hh + hl + lh in one fp32 MFMA accumulator.
// K-loop: { issue(chunk k+1 -> buf^1); compute(buf^0); barrier } -- the compiler's
// vmcnt(0) drain at the barrier lands AFTER compute, so staging overlaps MFMA.
// Grid (NB, T_/BM, B_), 256 threads (4 waves, each a 64x64 sub-tile).
__global__ __launch_bounds__(256) void mfma_argmax_kernel(
    const ushort* __restrict__ xh, const ushort* __restrict__ xl,
    const float* __restrict__ rnorm, const int* __restrict__ keep_idx,
    float* __restrict__ pb, float* __restrict__ ps, int* __restrict__ pk)
{
  // [stage][tile: Ah,Al,Bh,Bl][c-chunk 0..3][row 0..127][8 bf16] = 64 KiB
  __shared__ __align__(16) ushort lds[2][4][4][128][8];

  int b  = blockIdx.z;
  int m0 = blockIdx.y * BM;
  int n0 = blockIdx.x * BN;
  int tid = threadIdx.x;
  int lane = tid & 63, wave = tid >> 6;
  int quad = lane >> 4, col = lane & 15;
  int wm = wave >> 1, wn = wave & 1;

  int srow = tid & 127;
  int sc8  = (tid >> 7) * 8;   // element offset of first staged chunk

  const ushort* ga_h = xh + (size_t)(b * T_ + m0 + srow) * C_;
  const ushort* ga_l = xl + (size_t)(b * T_ + m0 + srow) * C_;
  int ktok_s = keep_idx[b * K_ + n0 + srow];
  const ushort* gb_h = xh + (size_t)(b * T_ + ktok_s) * C_;
  const ushort* gb_l = xl + (size_t)(b * T_ + ktok_s) * C_;

  int ldst = tid * 8;          // ushort offset of this thread's 16B slot

  float scale[4]; int ncand[4];
  #pragma unroll
  for (int j = 0; j < 4; j++) {
    int nn = n0 + wn * 64 + j * 16 + col;
    ncand[j] = nn;
    scale[j] = rnorm[b * T_ + keep_idx[b * K_ + nn]];
  }

  f32x4 acc[4][4];
  #pragma unroll
  for (int i = 0; i < 4; i++)
    #pragma unroll
    for (int j = 0; j < 4; j++) acc[i][j] = (f32x4)0.f;

  auto issue = [&](int k0, int st) {
    ushort* base = &lds[st][0][0][0][0];
    gload16(ga_h + k0 + sc8,      base + ldst);
    gload16(ga_h + k0 + 16 + sc8, base + ldst + 2048);
    gload16(ga_l + k0 + sc8,      base + 4096 + ldst);
    gload16(ga_l + k0 + 16 + sc8, base + 4096 + ldst + 2048);
    gload16(gb_h + k0 + sc8,      base + 8192 + ldst);
    gload16(gb_h + k0 + 16 + sc8, base + 8192 + ldst + 2048);
    gload16(gb_l + k0 + sc8,      base + 12288 + ldst);
    gload16(gb_l + k0 + 16 + sc8, base + 12288 + ldst + 2048);
  };

  issue(0, 0);
  __syncthreads();   // vmcnt(0) drain: chunk 0 resident

  for (int ks = 0; ks < C_ / BK; ks++) {
    int cur = ks & 1;
    if (ks < C_ / BK - 1) issue((ks + 1) * BK, cur ^ 1);  // prefetch overlaps compute

    bf16x8 fa_h[4], fa_l[4], fb_h[4], fb_l[4];
    #pragma unroll
    for (int i = 0; i < 4; i++) {
      int row = wm * 64 + i * 16 + col;
      fa_h[i] = *reinterpret_cast<const bf16x8*>(&lds[cur][0][quad][row][0]);
      fa_l[i] = *reinterpret_cast<const bf16x8*>(&lds[cur][1][quad][row][0]);
    }
    #pragma unroll
    for (int j = 0; j < 4; j++) {
      int row = wn * 64 + j * 16 + col;
      fb_h[j] = *reinterpret_cast<const bf16x8*>(&lds[cur][2][quad][row][0]);
      fb_l[j] = *reinterpret_cast<const bf16x8*>(&lds[cur][3][quad][row][0]);
    }
    #pragma unroll
    for (int i = 0; i < 4; i++)
      #pragma unroll
      for (int j = 0; j < 4; j++) {
        acc[i][j] = __builtin_amdgcn_mfma_f32_16x16x32_bf16(fa_h[i], fb_h[j], acc[i][j], 0, 0, 0);
        acc[i][j] = __builtin_amdgcn_mfma_f32_16x16x32_bf16(fa_h[i], fb_l[j], acc[i][j], 0, 0, 0);
        acc[i][j] = __builtin_amdgcn_mfma_f32_16x16x32_bf16(fa_l[i], fb_h[j], acc[i][j], 0, 0, 0);
      }
    __syncthreads();  // drains prefetch (overlapped) + protects buffer swap
  }

  // ---- epilogue: top-2 per token row over this block's 128 centers ----
  // Reductions overlaid on dead staging LDS (last barrier above orders reuse).
  float* redb   = (float*)(&lds[0][0][0][0][0]);   // [2][128]
  float* redsec = redb + 256;
  int*   redk   = (int*)(redb + 512);

  // C/D layout: col=lane&15 (n), row=quad*4+reg (m)
  #pragma unroll
  for (int i = 0; i < 4; i++) {
    #pragma unroll
    for (int r = 0; r < 4; r++) {
      float b1 = -FLT_MAX, b2 = -FLT_MAX; int k1 = 0;
      #pragma unroll
      for (int j = 0; j < 4; j++) {
        float v = acc[i][j][r] * scale[j];
        if (v > b1) { b2 = b1; b1 = v; k1 = ncand[j]; }
        else if (v > b2) b2 = v;
      }
      #pragma unroll
      for (int off = 1; off < 16; off <<= 1) {
        float ob1 = __shfl_xor(b1, off);
        float ob2 = __shfl_xor(b2, off);
        int   ok1 = __shfl_xor(k1, off);
        if (ob1 > b1 || (ob1 == b1 && ok1 < k1)) { b2 = fmaxf(b1, ob2); b1 = ob1; k1 = ok1; }
        else b2 = fmaxf(b2, ob1);
      }
      if (col == 0) {
        int tl = wm * 64 + i * 16 + quad * 4 + r;
        redb[wn * 128 + tl] = b1; redsec[wn * 128 + tl] = b2; redk[wn * 128 + tl] = k1;
      }
    }
  }
  __syncthreads();
  if (tid < 128) {
    float b1 = redb[tid], b2 = redsec[tid]; int k1 = redk[tid];
    float o1 = redb[128 + tid], o2 = redsec[128 + tid]; int ok = redk[128 + tid];
    if (o1 > b1) { b2 = fmaxf(b1, o2); b1 = o1; k1 = ok; }  // wn=1 range higher: ties keep wn=0
    else b2 = fmaxf(b2, o1);
    size_t p = ((size_t)(b * NB + blockIdx.x)) * T_ + m0 + tid;
    pb[p] = b1; ps[p] = b2; pk[p] = k1;
  }
}

// ---------------- kernel 3b: merge partials -> assign + refine queue ----------------
__global__ __launch_bounds__(256) void reduce2_kernel(
    const float* __restrict__ pb, const float* __restrict__ ps, const int* __restrict__ pk,
    const float* __restrict__ rnorm, const int* __restrict__ kpos,
    int* __restrict__ assign, int* __restrict__ rlist, int* __restrict__ nref)
{
  int idx = blockIdx.x * 256 + threadIdx.x;   // b*T + t
  int b = idx >> 12;
  float b1 = -FLT_MAX, b2 = -FLT_MAX; int k1 = 0;
  for (int nb = 0; nb < NB; nb++) {           // nb ascending => n ascending, '>' keeps first
    size_t p = ((size_t)(b * NB + nb)) * T_ + (idx & (T_ - 1));
    float v = pb[p], s = ps[p]; int k = pk[p];
    if (v > b1) { b2 = fmaxf(b1, s); b1 = v; k1 = k; }
    else b2 = fmaxf(b2, v);
  }
  int kp = kpos[idx];
  if (kp >= 0) assign[idx] = kp;
  else {
    assign[idx] = k1;
    if ((b1 - b2) * rnorm[idx] < REFINE_DELTA) {
      int qi = atomicAdd(nref, 1);
      rlist[qi] = idx;
    }
  }
}

// ---------------- kernel 3c: fp64 re-score of near-tie tokens ----------------
__global__ __launch_bounds__(256) void refine_kernel(
    const float* __restrict__ x, const double* __restrict__ sd,
    const int* __restrict__ keep_idx, const int* __restrict__ nref,
    const int* __restrict__ rlist, int* __restrict__ assign)
{
  __shared__ __align__(16) float xs[C_];
  __shared__ double rv[256];
  __shared__ int rk[256];
  int n = *nref;
  for (int qi = blockIdx.x; qi < n; qi += gridDim.x) {
    int bt = rlist[qi];
    int b = bt >> 12;
    const float* xb = x + (size_t)b * T_ * C_;
    const float* xt = xb + (size_t)(bt & (T_ - 1)) * C_;
    __syncthreads();
    for (int i = threadIdx.x; i < C_; i += 256) xs[i] = xt[i];
    __syncthreads();
    double bv = -DBL_MAX; int bk = 0x7fffffff;
    for (int k = threadIdx.x; k < K_; k += 256) {
      int kt = keep_idx[b * K_ + k];
      const float* xr = xb + (size_t)kt * C_;
      double s = 0.0;
      for (int c = 0; c < C_; c += 4) {
        float4 v = *reinterpret_cast<const float4*>(&xr[c]);
        s += (double)xs[c] * v.x + (double)xs[c+1] * v.y
           + (double)xs[c+2] * v.z + (double)xs[c+3] * v.w;
      }
      s /= sqrt(sd[b * T_ + kt]);
      if (s > bv || (s == bv && k < bk)) { bv = s; bk = k; }
    }
    rv[threadIdx.x] = bv; rk[threadIdx.x] = bk;
    __syncthreads();
    for (int off = 128; off > 0; off >>= 1) {
      if (threadIdx.x < off) {
        double v2 = rv[threadIdx.x + off]; int k2 = rk[threadIdx.x + off];
        if (v2 > rv[threadIdx.x] || (v2 == rv[threadIdx.x] && k2 < rk[threadIdx.x])) {
          rv[threadIdx.x] = v2; rk[threadIdx.x] = k2;
        }
      }
      __syncthreads();
    }
    if (threadIdx.x == 0) assign[bt] = rk[0];
    __syncthreads();
  }
}

// ---------------- kernels 4: counting-sort cluster lists ----------------
__global__ void count_kernel(const int* __restrict__ assign, int* __restrict__ cnt)
{
  int i = blockIdx.x * 256 + threadIdx.x;
  int b = i >> 12;
  atomicAdd(&cnt[b * K_ + assign[i]], 1);
}

__global__ __launch_bounds__(256) void scan_kernel(
    const int* __restrict__ cnt, int* __restrict__ offs, int* __restrict__ cursor)
{
  int b = blockIdx.x, tid = threadIdx.x;
  __shared__ int sums[256];
  int v[8], s = 0;
  int base = b * K_ + tid * 8;
  #pragma unroll
  for (int i = 0; i < 8; i++) { v[i] = cnt[base + i]; s += v[i]; }
  sums[tid] = s;
  __syncthreads();
  for (int off = 1; off < 256; off <<= 1) {
    int t2 = 0;
    if (tid >= off) t2 = sums[tid - off];
    __syncthreads();
    if (tid >= off) sums[tid] += t2;
    __syncthreads();
  }
  int run = (tid == 0) ? 0 : sums[tid - 1];
  #pragma unroll
  for (int i = 0; i < 8; i++) { offs[base + i] = run; cursor[base + i] = run; run += v[i]; }
}

__global__ void scatter_kernel(const int* __restrict__ assign,
                               int* __restrict__ cursor, int* __restrict__ lists)
{
  int i = blockIdx.x * 256 + threadIdx.x;
  int b = i >> 12, t = i & (T_ - 1);
  int p = atomicAdd(&cursor[b * K_ + assign[i]], 1);
  lists[b * T_ + p] = t;
}

// ---------------- kernel 5: segment mean + alpha blend ----------------
__global__ __launch_bounds__(256) void merge_kernel(
    const float* __restrict__ x, const int* __restrict__ keep_idx,
    const int* __restrict__ cnt, const int* __restrict__ offs,
    const int* __restrict__ lists, float* __restrict__ out)
{
  int b = blockIdx.y, k = blockIdx.x;
  int m = cnt[b * K_ + k], off = offs[b * K_ + k];
  const float* xb = x + (size_t)b * T_ * C_;
  int c4 = threadIdx.x * 4;
  float sx = 0.f, sy = 0.f, sz = 0.f, sw = 0.f;
  for (int i = 0; i < m; i++) {
    int tok = lists[b * T_ + off + i];
    float4 v = *reinterpret_cast<const float4*>(&xb[(size_t)tok * C_ + c4]);
    sx += v.x; sy += v.y; sz += v.z; sw += v.w;
  }
  int kt = keep_idx[b * K_ + k];
  float4 xk = *reinterpret_cast<const float4*>(&xb[(size_t)kt * C_ + c4]);
  float fm = (float)m;
  float4 o;
  o.x = 0.85f * xk.x + 0.15f * (sx / fm);
  o.y = 0.85f * xk.y + 0.15f * (sy / fm);
  o.z = 0.85f * xk.z + 0.15f * (sz / fm);
  o.w = 0.85f * xk.w + 0.15f * (sw / fm);
  *reinterpret_cast<float4*>(&out[((size_t)b * K_ + k) * C_ + c4]) = o;
}

// ---------------- launch ----------------
extern "C" void kernel_launch(void* const* d_in, const int* in_sizes, int n_in,
                              void* d_out, int out_size, void* d_ws, size_t ws_size,
                              hipStream_t stream)
{
  const float* x = (const float*)d_in[0];
  float* out = (float*)d_out;

  char* w = (char*)d_ws;
  ushort* xh    = (ushort*)w;  w += sizeof(ushort) * (size_t)B_ * T_ * C_;  // 67 MB
  ushort* xl    = (ushort*)w;  w += sizeof(ushort) * (size_t)B_ * T_ * C_;  // 67 MB
  float* pb     = (float*)w;   w += sizeof(float) * (size_t)B_ * NB * T_;   // 2 MB
  float* ps     = (float*)w;   w += sizeof(float) * (size_t)B_ * NB * T_;
  int*   pk     = (int*)w;     w += sizeof(int) * (size_t)B_ * NB * T_;
  double* sd    = (double*)w;  w += sizeof(double) * B_ * T_;
  float* rnorm  = (float*)w;   w += sizeof(float) * B_ * T_;
  int* flag     = (int*)w;     w += sizeof(int) * B_ * T_;
  int* kpos     = (int*)w;     w += sizeof(int) * B_ * T_;
  int* keep_idx = (int*)w;     w += sizeof(int) * B_ * K_;
  int* assign   = (int*)w;     w += sizeof(int) * B_ * T_;
  int* cnt      = (int*)w;     w += sizeof(int) * B_ * K_;
  int* offs     = (int*)w;     w += sizeof(int) * B_ * K_;
  int* cursor   = (int*)w;     w += sizeof(int) * B_ * K_;
  int* lists    = (int*)w;     w += sizeof(int) * B_ * T_;
  int* rlist    = (int*)w;     w += sizeof(int) * B_ * T_;
  int* nref     = (int*)w;     w += 256;

  split_score_kernel<<<B_ * T_, 256, 0, stream>>>(x, xh, xl, sd, rnorm);
  rank_kernel<<<dim3(T_ / 128, B_), 256, 0, stream>>>(sd, flag);
  select_kernel<<<B_, 256, 0, stream>>>(flag, kpos, keep_idx);
  zero_kernel<<<(B_ * K_ + 255) / 256, 256, 0, stream>>>(cnt, nref);
  mfma_argmax_kernel<<<dim3(NB, T_ / BM, B_), 256, 0, stream>>>(
      xh, xl, rnorm, keep_idx, pb, ps, pk);
  reduce2_kernel<<<B_ * T_ / 256, 256, 0, stream>>>(
      pb, ps, pk, rnorm, kpos, assign, rlist, nref);
  refine_kernel<<<256, 256, 0, stream>>>(x, sd, keep_idx, nref, rlist, assign);
  count_kernel<<<B_ * T_ / 256, 256, 0, stream>>>(assign, cnt);
  scan_kernel<<<B_, 256, 0, stream>>>(cnt, offs, cursor);
  scatter_kernel<<<B_ * T_ / 256, 256, 0, stream>>>(assign, cursor, lists);
  merge_kernel<<<dim3(K_, B_), 256, 0, stream>>>(x, keep_idx, cnt, offs, lists, out);
}

// Round 4
// 690.044 us; speedup vs baseline: 4.4829x; 1.7433x over previous
//
#include <hip/hip_runtime.h>
#include <hip/hip_bf16.h>
#include <float.h>
#include <math.h>

// Shapes fixed by setup_inputs(): B=8, T=4096, C=1024, requested_r=2048.
constexpr int B_ = 8;
constexpr int T_ = 4096;
constexpr int C_ = 1024;
constexpr int K_ = 2048;

constexpr int BM = 128, BN = 128, BK = 32;
constexpr int NB = K_ / BN;            // 16 n-blocks
// fp16 cosine-score noise sigma ~1.4e-5; delta = 4e-4 ~ 20 sigma of gap error.
// P(gap < delta) ~ 2% -> ~550 flagged tokens, each costing ~2 fp64 dots (cheap).
constexpr float REFINE_DELTA = 4e-4f;

typedef _Float16 f16x8 __attribute__((ext_vector_type(8)));
typedef float    f32x4 __attribute__((ext_vector_type(4)));

__device__ __forceinline__ void gload16(const ushort* g, ushort* l) {
  __builtin_amdgcn_global_load_lds(
      (const __attribute__((address_space(1))) unsigned int*)g,
      (__attribute__((address_space(3))) unsigned int*)l, 16, 0, 0);
}

// ---------------- kernel 0: fused fp16 cast + fp64 squared norm ----------------
__global__ __launch_bounds__(256) void split_score_kernel(
    const float* __restrict__ x, ushort* __restrict__ xh,
    double* __restrict__ sd, float* __restrict__ rnorm)
{
  int row = blockIdx.x;                 // b*T + t
  size_t base = (size_t)row * C_;
  int i4 = threadIdx.x * 4;
  float4 v = *reinterpret_cast<const float4*>(&x[base + i4]);
  ushort4 h;
  { _Float16 a = (_Float16)v.x; h.x = *(ushort*)&a; }
  { _Float16 a = (_Float16)v.y; h.y = *(ushort*)&a; }
  { _Float16 a = (_Float16)v.z; h.z = *(ushort*)&a; }
  { _Float16 a = (_Float16)v.w; h.w = *(ushort*)&a; }
  *reinterpret_cast<ushort4*>(&xh[base + i4]) = h;
  double s = (double)v.x * v.x + (double)v.y * v.y
           + (double)v.z * v.z + (double)v.w * v.w;
  #pragma unroll
  for (int off = 32; off > 0; off >>= 1) s += __shfl_down(s, off);
  __shared__ double ws4[4];
  int lane = threadIdx.x & 63, wave = threadIdx.x >> 6;
  if (lane == 0) ws4[wave] = s;
  __syncthreads();
  if (threadIdx.x == 0) {
    double t = ws4[0] + ws4[1] + ws4[2] + ws4[3];
    sd[row] = t;
    rnorm[row] = (float)(1.0 / (sqrt(t) + 1e-12));
  }
}

// ---------------- kernel 2a: rank-count top-K flags (fp64 keys, exact order) ----
__global__ __launch_bounds__(256) void rank_kernel(
    const double* __restrict__ sd, int* __restrict__ flag)
{
  int b = blockIdx.y;
  __shared__ double sh[T_];
  for (int i = threadIdx.x; i < T_; i += 256)
    sh[i] = (i == 0) ? DBL_MAX : sd[b * T_ + i];   // CLS protection
  __syncthreads();
  int t = blockIdx.x * 128 + (threadIdx.x >> 1);
  int half = threadIdx.x & 1;
  double key = sh[t];
  int cnt = 0;
  int j0 = half * 2048;
  #pragma unroll 4
  for (int jj = 0; jj < 2048; jj++) {
    int j = j0 + jj;
    double sj = sh[j];
    cnt += (sj > key) || (sj == key && j < t);     // (score desc, idx asc)
  }
  cnt += __shfl_xor(cnt, 1);
  if (half == 0) flag[b * T_ + t] = (cnt < K_) ? 1 : 0;
}

// ---------------- kernel 2b: prefix over flags -> keep_idx (sorted), kpos -------
__global__ __launch_bounds__(256) void select_kernel(
    const int* __restrict__ flag, int* __restrict__ kpos, int* __restrict__ keep_idx)
{
  int b = blockIdx.x, tid = threadIdx.x;
  __shared__ int sums[256];
  int f[16], s = 0;
  int base = b * T_ + tid * 16;
  #pragma unroll
  for (int i = 0; i < 16; i++) { f[i] = flag[base + i]; s += f[i]; }
  sums[tid] = s;
  __syncthreads();
  for (int off = 1; off < 256; off <<= 1) {
    int v = 0;
    if (tid >= off) v = sums[tid - off];
    __syncthreads();
    if (tid >= off) sums[tid] += v;
    __syncthreads();
  }
  int run = (tid == 0) ? 0 : sums[tid - 1];
  #pragma unroll
  for (int i = 0; i < 16; i++) {
    int t = tid * 16 + i;
    if (f[i]) { keep_idx[b * K_ + run] = t; kpos[b * T_ + t] = run; run++; }
    else kpos[b * T_ + t] = -1;
  }
}

// ---------------- zero scratch ----------------
__global__ void zero_kernel(int* __restrict__ cnt, int* __restrict__ nref)
{
  int i = blockIdx.x * 256 + threadIdx.x;
  if (i < B_ * K_) cnt[i] = 0;
  if (i == 0) *nref = 0;
}

// ---------------- kernel 3: fp16 MFMA similarity, double-buffered staging -------
// Single hh pass (fp16 input rounding handled by candidate-limited fp64 refine).
// Grid (NB, T_/BM, B_), 256 threads (4 waves, each a 64x64 sub-tile).
__global__ __launch_bounds__(256) void mfma_argmax_kernel(
    const ushort* __restrict__ xh, const float* __restrict__ rnorm,
    const int* __restrict__ keep_idx,
    float* __restrict__ pb, float* __restrict__ ps, int* __restrict__ pk)
{
  // [stage][A/B][c-chunk 0..3][row 0..127][8 f16] = 32 KiB
  __shared__ __align__(16) ushort lds[2][2][4][128][8];

  int b  = blockIdx.z;
  int m0 = blockIdx.y * BM;
  int n0 = blockIdx.x * BN;
  int tid = threadIdx.x;
  int lane = tid & 63, wave = tid >> 6;
  int quad = lane >> 4, col = lane & 15;
  int wm = wave >> 1, wn = wave & 1;

  int srow = tid & 127;
  int sc8  = (tid >> 7) * 8;   // k-element offset of first staged 16B slot

  const ushort* ga = xh + (size_t)(b * T_ + m0 + srow) * C_;
  int ktok_s = keep_idx[b * K_ + n0 + srow];
  const ushort* gb = xh + (size_t)(b * T_ + ktok_s) * C_;

  int ldst = tid * 8;          // ushort offset within one [4][128][8] plane

  float scale[4]; int ncand[4];
  #pragma unroll
  for (int j = 0; j < 4; j++) {
    int nn = n0 + wn * 64 + j * 16 + col;
    ncand[j] = nn;
    scale[j] = rnorm[b * T_ + keep_idx[b * K_ + nn]];
  }

  f32x4 acc[4][4];
  #pragma unroll
  for (int i = 0; i < 4; i++)
    #pragma unroll
    for (int j = 0; j < 4; j++) acc[i][j] = (f32x4)0.f;

  auto issue = [&](int k0, int st) {
    ushort* base = &lds[st][0][0][0][0];
    gload16(ga + k0 + sc8,      base + ldst);          // A chunks {0,1}|{2,3}
    gload16(ga + k0 + 16 + sc8, base + ldst + 2048);
    gload16(gb + k0 + sc8,      base + 4096 + ldst);   // B plane
    gload16(gb + k0 + 16 + sc8, base + 4096 + ldst + 2048);
  };

  issue(0, 0);
  __syncthreads();   // vmcnt(0) drain: chunk 0 resident

  for (int ks = 0; ks < C_ / BK; ks++) {
    int cur = ks & 1;
    if (ks < C_ / BK - 1) issue((ks + 1) * BK, cur ^ 1);  // prefetch overlaps compute

    f16x8 fa[4], fb[4];
    #pragma unroll
    for (int i = 0; i < 4; i++) {
      int row = wm * 64 + i * 16 + col;
      fa[i] = *reinterpret_cast<const f16x8*>(&lds[cur][0][quad][row][0]);
    }
    #pragma unroll
    for (int j = 0; j < 4; j++) {
      int row = wn * 64 + j * 16 + col;
      fb[j] = *reinterpret_cast<const f16x8*>(&lds[cur][1][quad][row][0]);
    }
    #pragma unroll
    for (int i = 0; i < 4; i++)
      #pragma unroll
      for (int j = 0; j < 4; j++)
        acc[i][j] = __builtin_amdgcn_mfma_f32_16x16x32_f16(fa[i], fb[j], acc[i][j], 0, 0, 0);
    __syncthreads();  // drains prefetch (overlapped) + protects buffer swap
  }

  // ---- epilogue: top-2 per token row over this block's 128 centers ----
  float* redb   = (float*)(&lds[0][0][0][0][0]);   // overlay on dead staging LDS
  float* redsec = redb + 256;
  int*   redk   = (int*)(redb + 512);

  // C/D layout: col=lane&15 (n), row=quad*4+reg (m)
  #pragma unroll
  for (int i = 0; i < 4; i++) {
    #pragma unroll
    for (int r = 0; r < 4; r++) {
      float b1 = -FLT_MAX, b2 = -FLT_MAX; int k1 = 0;
      #pragma unroll
      for (int j = 0; j < 4; j++) {
        float v = acc[i][j][r] * scale[j];
        if (v > b1) { b2 = b1; b1 = v; k1 = ncand[j]; }
        else if (v > b2) b2 = v;
      }
      #pragma unroll
      for (int off = 1; off < 16; off <<= 1) {
        float ob1 = __shfl_xor(b1, off);
        float ob2 = __shfl_xor(b2, off);
        int   ok1 = __shfl_xor(k1, off);
        if (ob1 > b1 || (ob1 == b1 && ok1 < k1)) { b2 = fmaxf(b1, ob2); b1 = ob1; k1 = ok1; }
        else b2 = fmaxf(b2, ob1);
      }
      if (col == 0) {
        int tl = wm * 64 + i * 16 + quad * 4 + r;
        redb[wn * 128 + tl] = b1; redsec[wn * 128 + tl] = b2; redk[wn * 128 + tl] = k1;
      }
    }
  }
  __syncthreads();
  if (tid < 128) {
    float b1 = redb[tid], b2 = redsec[tid]; int k1 = redk[tid];
    float o1 = redb[128 + tid], o2 = redsec[128 + tid]; int ok = redk[128 + tid];
    if (o1 > b1) { b2 = fmaxf(b1, o2); b1 = o1; k1 = ok; }  // ties keep lower-n wn=0
    else b2 = fmaxf(b2, o1);
    size_t p = ((size_t)(b * NB + blockIdx.x)) * T_ + m0 + tid;
    pb[p] = b1; ps[p] = b2; pk[p] = k1;
  }
}

// ---------------- kernel 3b: merge partials -> assign + refine queue ------------
__global__ __launch_bounds__(256) void reduce2_kernel(
    const float* __restrict__ pb, const float* __restrict__ ps, const int* __restrict__ pk,
    const float* __restrict__ rnorm, const int* __restrict__ kpos,
    int* __restrict__ assign, int* __restrict__ rlist, int* __restrict__ nref)
{
  int idx = blockIdx.x * 256 + threadIdx.x;   // b*T + t
  int b = idx >> 12;
  float b1 = -FLT_MAX, b2 = -FLT_MAX; int k1 = 0;
  for (int nb = 0; nb < NB; nb++) {           // nb ascending => n ascending
    size_t p = ((size_t)(b * NB + nb)) * T_ + (idx & (T_ - 1));
    float v = pb[p], s = ps[p]; int k = pk[p];
    if (v > b1) { b2 = fmaxf(b1, s); b1 = v; k1 = k; }
    else b2 = fmaxf(b2, v);
  }
  int kp = kpos[idx];
  if (kp >= 0) assign[idx] = kp;
  else {
    assign[idx] = k1;
    if ((b1 - b2) * rnorm[idx] < REFINE_DELTA) {
      int qi = atomicAdd(nref, 1);
      rlist[qi] = idx;
    }
  }
}

// ---------------- kernel 3c: candidate-limited fp64 re-score -------------------
// Per flagged token: fp64-rescore only block-winners with pb >= b1-thr; if a
// block's second-best is also >= b1-thr, scan that whole 128-block (a provable
// superset of every candidate within thr of the true max).
__global__ __launch_bounds__(256) void refine_kernel(
    const float* __restrict__ x, const double* __restrict__ sd,
    const int* __restrict__ keep_idx, const float* __restrict__ rnorm,
    const float* __restrict__ pb, const float* __restrict__ ps, const int* __restrict__ pk,
    const int* __restrict__ nref, const int* __restrict__ rlist, int* __restrict__ assign)
{
  __shared__ __align__(16) float xs[C_];
  __shared__ int cand[K_];
  __shared__ int ncand_s;
  __shared__ double wv[4];
  __shared__ int wk[4];
  int n = *nref;
  int lane = threadIdx.x & 63, wave = threadIdx.x >> 6;
  for (int qi = blockIdx.x; qi < n; qi += gridDim.x) {
    int bt = rlist[qi];
    int b = bt >> 12, t = bt & (T_ - 1);
    __syncthreads();   // protect previous iteration's LDS
    const float* xt = x + ((size_t)b * T_ + t) * C_;
    for (int i = threadIdx.x; i < C_; i += 256) xs[i] = xt[i];
    if (threadIdx.x == 0) {
      float b1 = -FLT_MAX;
      for (int nb = 0; nb < NB; nb++) {
        float v = pb[((size_t)(b * NB + nb)) * T_ + t];
        if (v > b1) b1 = v;
      }
      float thr = b1 - REFINE_DELTA / rnorm[bt];   // cosine delta -> raw score units
      int nc = 0;
      for (int nb = 0; nb < NB; nb++) {
        size_t p = ((size_t)(b * NB + nb)) * T_ + t;
        if (pb[p] >= thr) {
          if (ps[p] >= thr) { for (int j = 0; j < BN; j++) cand[nc++] = nb * BN + j; }
          else cand[nc++] = pk[p];
        }
      }
      ncand_s = nc;
    }
    __syncthreads();
    int nc = ncand_s;
    double bv = -DBL_MAX; int bk = 0x7fffffff;
    for (int ci = wave; ci < nc; ci += 4) {
      int k = cand[ci];
      int kt = keep_idx[b * K_ + k];
      const float* xr = x + ((size_t)b * T_ + kt) * C_;
      double s = 0.0;
      int c0 = lane * 16;
      #pragma unroll
      for (int c = 0; c < 16; c += 4) {
        float4 v = *reinterpret_cast<const float4*>(&xr[c0 + c]);
        s += (double)xs[c0 + c]     * v.x + (double)xs[c0 + c + 1] * v.y
           + (double)xs[c0 + c + 2] * v.z + (double)xs[c0 + c + 3] * v.w;
      }
      #pragma unroll
      for (int off = 32; off > 0; off >>= 1) s += __shfl_down(s, off);
      s = __shfl(s, 0);
      s /= sqrt(sd[b * T_ + kt]);
      if (s > bv || (s == bv && k < bk)) { bv = s; bk = k; }
    }
    if (lane == 0) { wv[wave] = bv; wk[wave] = bk; }
    __syncthreads();
    if (threadIdx.x == 0) {
      double fb = wv[0]; int fk = wk[0];
      for (int w2 = 1; w2 < 4; w2++)
        if (wv[w2] > fb || (wv[w2] == fb && wk[w2] < fk)) { fb = wv[w2]; fk = wk[w2]; }
      assign[bt] = fk;
    }
  }
}

// ---------------- kernels 4: counting-sort cluster lists ----------------
__global__ void count_kernel(const int* __restrict__ assign, int* __restrict__ cnt)
{
  int i = blockIdx.x * 256 + threadIdx.x;
  int b = i >> 12;
  atomicAdd(&cnt[b * K_ + assign[i]], 1);
}

__global__ __launch_bounds__(256) void scan_kernel(
    const int* __restrict__ cnt, int* __restrict__ offs, int* __restrict__ cursor)
{
  int b = blockIdx.x, tid = threadIdx.x;
  __shared__ int sums[256];
  int v[8], s = 0;
  int base = b * K_ + tid * 8;
  #pragma unroll
  for (int i = 0; i < 8; i++) { v[i] = cnt[base + i]; s += v[i]; }
  sums[tid] = s;
  __syncthreads();
  for (int off = 1; off < 256; off <<= 1) {
    int t2 = 0;
    if (tid >= off) t2 = sums[tid - off];
    __syncthreads();
    if (tid >= off) sums[tid] += t2;
    __syncthreads();
  }
  int run = (tid == 0) ? 0 : sums[tid - 1];
  #pragma unroll
  for (int i = 0; i < 8; i++) { offs[base + i] = run; cursor[base + i] = run; run += v[i]; }
}

__global__ void scatter_kernel(const int* __restrict__ assign,
                               int* __restrict__ cursor, int* __restrict__ lists)
{
  int i = blockIdx.x * 256 + threadIdx.x;
  int b = i >> 12, t = i & (T_ - 1);
  int p = atomicAdd(&cursor[b * K_ + assign[i]], 1);
  lists[b * T_ + p] = t;
}

// ---------------- kernel 5: segment mean + alpha blend ----------------
__global__ __launch_bounds__(256) void merge_kernel(
    const float* __restrict__ x, const int* __restrict__ keep_idx,
    const int* __restrict__ cnt, const int* __restrict__ offs,
    const int* __restrict__ lists, float* __restrict__ out)
{
  int b = blockIdx.y, k = blockIdx.x;
  int m = cnt[b * K_ + k], off = offs[b * K_ + k];
  const float* xb = x + (size_t)b * T_ * C_;
  int c4 = threadIdx.x * 4;
  float sx = 0.f, sy = 0.f, sz = 0.f, sw = 0.f;
  for (int i = 0; i < m; i++) {
    int tok = lists[b * T_ + off + i];
    float4 v = *reinterpret_cast<const float4*>(&xb[(size_t)tok * C_ + c4]);
    sx += v.x; sy += v.y; sz += v.z; sw += v.w;
  }
  int kt = keep_idx[b * K_ + k];
  float4 xk = *reinterpret_cast<const float4*>(&xb[(size_t)kt * C_ + c4]);
  float fm = (float)m;
  float4 o;
  o.x = 0.85f * xk.x + 0.15f * (sx / fm);
  o.y = 0.85f * xk.y + 0.15f * (sy / fm);
  o.z = 0.85f * xk.z + 0.15f * (sz / fm);
  o.w = 0.85f * xk.w + 0.15f * (sw / fm);
  *reinterpret_cast<float4*>(&out[((size_t)b * K_ + k) * C_ + c4]) = o;
}

// ---------------- launch ----------------
extern "C" void kernel_launch(void* const* d_in, const int* in_sizes, int n_in,
                              void* d_out, int out_size, void* d_ws, size_t ws_size,
                              hipStream_t stream)
{
  const float* x = (const float*)d_in[0];
  float* out = (float*)d_out;

  char* w = (char*)d_ws;
  ushort* xh    = (ushort*)w;  w += sizeof(ushort) * (size_t)B_ * T_ * C_;  // 67 MB
  float* pb     = (float*)w;   w += sizeof(float) * (size_t)B_ * NB * T_;   // 2 MB
  float* ps     = (float*)w;   w += sizeof(float) * (size_t)B_ * NB * T_;
  int*   pk     = (int*)w;     w += sizeof(int) * (size_t)B_ * NB * T_;
  double* sd    = (double*)w;  w += sizeof(double) * B_ * T_;
  float* rnorm  = (float*)w;   w += sizeof(float) * B_ * T_;
  int* flag     = (int*)w;     w += sizeof(int) * B_ * T_;
  int* kpos     = (int*)w;     w += sizeof(int) * B_ * T_;
  int* keep_idx = (int*)w;     w += sizeof(int) * B_ * K_;
  int* assign   = (int*)w;     w += sizeof(int) * B_ * T_;
  int* cnt      = (int*)w;     w += sizeof(int) * B_ * K_;
  int* offs     = (int*)w;     w += sizeof(int) * B_ * K_;
  int* cursor   = (int*)w;     w += sizeof(int) * B_ * K_;
  int* lists    = (int*)w;     w += sizeof(int) * B_ * T_;
  int* rlist    = (int*)w;     w += sizeof(int) * B_ * T_;
  int* nref     = (int*)w;     w += 256;

  split_score_kernel<<<B_ * T_, 256, 0, stream>>>(x, xh, sd, rnorm);
  rank_kernel<<<dim3(T_ / 128, B_), 256, 0, stream>>>(sd, flag);
  select_kernel<<<B_, 256, 0, stream>>>(flag, kpos, keep_idx);
  zero_kernel<<<(B_ * K_ + 255) / 256, 256, 0, stream>>>(cnt, nref);
  mfma_argmax_kernel<<<dim3(NB, T_ / BM, B_), 256, 0, stream>>>(
      xh, rnorm, keep_idx, pb, ps, pk);
  reduce2_kernel<<<B_ * T_ / 256, 256, 0, stream>>>(
      pb, ps, pk, rnorm, kpos, assign, rlist, nref);
  refine_kernel<<<256, 256, 0, stream>>>(
      x, sd, keep_idx, rnorm, pb, ps, pk, nref, rlist, assign);
  count_kernel<<<B_ * T_ / 256, 256, 0, stream>>>(assign, cnt);
  scan_kernel<<<B_, 256, 0, stream>>>(cnt, offs, cursor);
  scatter_kernel<<<B_ * T_ / 256, 256, 0, stream>>>(assign, cursor, lists);
  merge_kernel<<<dim3(K_, B_), 256, 0, stream>>>(x, keep_idx, cnt, offs, lists, out);
}